// Round 9
// baseline (422.270 us; speedup 1.0000x reference)
//
#include <hip/hip_runtime.h>
#include <cstdint>

// Zoom-aware MSA, MI355X/gfx950. Inputs fp32, output fp32.
// R13: GEMMs ported to the 256^2 8-wave deep-phase structure (T3+T4 regime):
// 512 threads (2Mx4N waves), per-wave C 128x64, BK=64 as two m97-format 32-K
// halves (layout identical to proven R8 staging), double-buffered 128KB LDS,
// 4 phases per K-tile {2x glds(tile kt+1) || ds_read quadrant || setprio+16
// MFMA}, ONE vmcnt(0)+barrier per K-tile (4-phase latency cover; A staged
// first, L2-resident B last). attn/cvts unchanged from R12.

#define SQ   1024
#define HID  1024
#define CEXP 0.18033688f      // (1/sqrt(64)) * log2(e)
#define LOG2E 1.44269504f

typedef __attribute__((ext_vector_type(8))) __bf16 bf16x8;
typedef __attribute__((ext_vector_type(4))) float  floatx4;

__device__ __forceinline__ float b2f(unsigned short x) {
    return __builtin_bit_cast(float, (uint32_t)x << 16);
}
__device__ __forceinline__ unsigned short f2bf(float f) {
    uint32_t u = __builtin_bit_cast(uint32_t, f);
    u += 0x7fffu + ((u >> 16) & 1u);          // RTNE
    return (unsigned short)(u >> 16);
}

// async global->LDS, 16B per lane; LDS dest = wave-uniform base + lane*16.
__device__ __forceinline__ void glds16(const void* g, void* l) {
    __builtin_amdgcn_global_load_lds(
        (const __attribute__((address_space(1))) void*)g,
        (__attribute__((address_space(3))) void*)l, 16, 0, 0);
}

// fp32 -> bf16 elementwise with scale, n % 4 == 0.
__global__ void cvt(const float* __restrict__ s, unsigned short* __restrict__ d,
                    int n4, float scale) {
    const int i = blockIdx.x * blockDim.x + threadIdx.x;
    if (i >= n4) return;
    const floatx4 v = *(const floatx4*)(s + 4 * (size_t)i);
    uint32_t lo = (uint32_t)f2bf(v[0] * scale) | ((uint32_t)f2bf(v[1] * scale) << 16);
    uint32_t hi = (uint32_t)f2bf(v[2] * scale) | ((uint32_t)f2bf(v[3] * scale) << 16);
    ((uint2*)d)[i] = make_uint2(lo, hi);
}

// 3-tensor fp32 -> bf16 (q,k,v) in one launch; blockIdx.y selects tensor.
__global__ void cvt3(const float* __restrict__ s0, const float* __restrict__ s1,
                     const float* __restrict__ s2, unsigned short* __restrict__ d0,
                     unsigned short* __restrict__ d1, unsigned short* __restrict__ d2,
                     int n4) {
    const int i = blockIdx.x * blockDim.x + threadIdx.x;
    if (i >= n4) return;
    const int z = blockIdx.y;
    const float* s = z == 0 ? s0 : (z == 1 ? s1 : s2);
    unsigned short* d = z == 0 ? d0 : (z == 1 ? d1 : d2);
    const floatx4 v = *(const floatx4*)(s + 4 * (size_t)i);
    uint32_t lo = (uint32_t)f2bf(v[0]) | ((uint32_t)f2bf(v[1]) << 16);
    uint32_t hi = (uint32_t)f2bf(v[2]) | ((uint32_t)f2bf(v[3]) << 16);
    ((uint2*)d)[i] = make_uint2(lo, hi);
}

// 4 weight matrices fp32 -> bf16 in one launch; blockIdx.y selects.
__global__ void cvt4(const float* __restrict__ s0, const float* __restrict__ s1,
                     const float* __restrict__ s2, const float* __restrict__ s3,
                     unsigned short* __restrict__ d0, unsigned short* __restrict__ d1,
                     unsigned short* __restrict__ d2, unsigned short* __restrict__ d3,
                     int n4) {
    const int i = blockIdx.x * blockDim.x + threadIdx.x;
    if (i >= n4) return;
    const int z = blockIdx.y;
    const float* s = z == 0 ? s0 : (z == 1 ? s1 : (z == 2 ? s2 : s3));
    unsigned short* d = z == 0 ? d0 : (z == 1 ? d1 : (z == 2 ? d2 : d3));
    const floatx4 v = *(const floatx4*)(s + 4 * (size_t)i);
    uint32_t lo = (uint32_t)f2bf(v[0]) | ((uint32_t)f2bf(v[1]) << 16);
    uint32_t hi = (uint32_t)f2bf(v[2]) | ((uint32_t)f2bf(v[3]) << 16);
    ((uint2*)d)[i] = make_uint2(lo, hi);
}

// 256x256-tile, 8-wave, BK=64 GEMM core. C = A[M,1024] @ Bw[1024,1024]^T + bias.
// LDS per K-tile: A,B each 2 half-K subtiles in m97 region format
// (region = 16 rows x 32 K, [quad][c][8] layout; glds dest = base + lane*16).
// trans: store [row>>10][n][row&1023] bf16. outF32: fp32 store to C+cOff.
__device__ __forceinline__ void gemm256_core(
    const short* __restrict__ A, const short* __restrict__ Bw,
    const float* __restrict__ bias, void* __restrict__ C, size_t cOff,
    int bm, int bn, bool trans, bool outF32,
    short (*As2)[16384], short (*Bs2)[16384])
{
    const int tid = threadIdx.x;
    const int wid = tid >> 6, lane = tid & 63;
    const int quad = lane >> 4, cc = lane & 15;
    const int wr = wid >> 2, wc = wid & 3;          // 2M x 4N wave grid

    // staging assignment: waves 0-3 -> kh=0, waves 4-7 -> kh=1; 4 regions each
    const int skh = wid >> 2;
    const int sr0 = (wid & 3) * 4;
    const size_t AU = (size_t)16 * HID;             // 16-row stride between units

    const short* ag = A  + (size_t)(bm * 256 + sr0 * 16 + cc) * HID + skh * 32 + quad * 8;
    const short* bg = Bw + (size_t)(bn * 256 + sr0 * 16 + cc) * HID + skh * 32 + quad * 8;
    const int dA = skh * 8192 + sr0 * 512;          // dest short-offset base
    const int dB = dA;

    floatx4 acc[8][4] = {};

    // prologue: stage tile 0 into buffer 0
#pragma unroll
    for (int u = 0; u < 4; ++u) glds16(ag + u * AU, As2[0] + dA + u * 512);
#pragma unroll
    for (int u = 0; u < 4; ++u) glds16(bg + u * AU, Bs2[0] + dB + u * 512);
    ag += 64; bg += 64;

    for (int kt = 0; kt < 16; ++kt) {
        const int b = kt & 1;
        asm volatile("s_waitcnt vmcnt(0)" ::: "memory");   // tile kt landed
        __builtin_amdgcn_s_barrier();                      // visible to all waves
        __builtin_amdgcn_sched_barrier(0);
        const bool st = (kt < 15);
        short* Ad = As2[b ^ 1];
        short* Bd = Bs2[b ^ 1];
        const short* Ab = As2[b];
        const short* Bb = Bs2[b];

        bf16x8 aF[4][2], bF0[2][2], bF1[2][2];

        // ---- phase 0: stage A u0,u1 ; read aF(ih=0), bF0 ; MFMA (0,0) ----
        if (st) { glds16(ag + 0 * AU, Ad + dA + 0 * 512);
                  glds16(ag + 1 * AU, Ad + dA + 1 * 512); }
#pragma unroll
        for (int i = 0; i < 4; ++i)
#pragma unroll
            for (int kh = 0; kh < 2; ++kh)
                aF[i][kh] = *(const bf16x8*)(Ab + kh * 8192 + (wr * 8 + i) * 512 + lane * 8);
#pragma unroll
        for (int j = 0; j < 2; ++j)
#pragma unroll
            for (int kh = 0; kh < 2; ++kh)
                bF0[j][kh] = *(const bf16x8*)(Bb + kh * 8192 + (wc * 4 + j) * 512 + lane * 8);
        __builtin_amdgcn_s_setprio(1);
#pragma unroll
        for (int i = 0; i < 4; ++i)
#pragma unroll
            for (int j = 0; j < 2; ++j)
#pragma unroll
                for (int kh = 0; kh < 2; ++kh)
                    acc[i][j] = __builtin_amdgcn_mfma_f32_16x16x32_bf16(aF[i][kh], bF0[j][kh], acc[i][j], 0, 0, 0);
        __builtin_amdgcn_s_setprio(0);

        // ---- phase 1: stage A u2,u3 ; read bF1 ; MFMA (0,1) ----
        if (st) { glds16(ag + 2 * AU, Ad + dA + 2 * 512);
                  glds16(ag + 3 * AU, Ad + dA + 3 * 512); }
#pragma unroll
        for (int j = 0; j < 2; ++j)
#pragma unroll
            for (int kh = 0; kh < 2; ++kh)
                bF1[j][kh] = *(const bf16x8*)(Bb + kh * 8192 + (wc * 4 + 2 + j) * 512 + lane * 8);
        __builtin_amdgcn_s_setprio(1);
#pragma unroll
        for (int i = 0; i < 4; ++i)
#pragma unroll
            for (int j = 0; j < 2; ++j)
#pragma unroll
                for (int kh = 0; kh < 2; ++kh)
                    acc[i][2 + j] = __builtin_amdgcn_mfma_f32_16x16x32_bf16(aF[i][kh], bF1[j][kh], acc[i][2 + j], 0, 0, 0);
        __builtin_amdgcn_s_setprio(0);

        // ---- phase 2: stage B u0,u1 ; read aF(ih=1) ; MFMA (1,0) ----
        if (st) { glds16(bg + 0 * AU, Bd + dB + 0 * 512);
                  glds16(bg + 1 * AU, Bd + dB + 1 * 512); }
#pragma unroll
        for (int i = 0; i < 4; ++i)
#pragma unroll
            for (int kh = 0; kh < 2; ++kh)
                aF[i][kh] = *(const bf16x8*)(Ab + kh * 8192 + (wr * 8 + 4 + i) * 512 + lane * 8);
        __builtin_amdgcn_s_setprio(1);
#pragma unroll
        for (int i = 0; i < 4; ++i)
#pragma unroll
            for (int j = 0; j < 2; ++j)
#pragma unroll
                for (int kh = 0; kh < 2; ++kh)
                    acc[4 + i][j] = __builtin_amdgcn_mfma_f32_16x16x32_bf16(aF[i][kh], bF0[j][kh], acc[4 + i][j], 0, 0, 0);
        __builtin_amdgcn_s_setprio(0);

        // ---- phase 3: stage B u2,u3 ; MFMA (1,1) ----
        if (st) { glds16(bg + 2 * AU, Bd + dB + 2 * 512);
                  glds16(bg + 3 * AU, Bd + dB + 3 * 512);
                  ag += 64; bg += 64; }
        __builtin_amdgcn_s_setprio(1);
#pragma unroll
        for (int i = 0; i < 4; ++i)
#pragma unroll
            for (int j = 0; j < 2; ++j)
#pragma unroll
                for (int kh = 0; kh < 2; ++kh)
                    acc[4 + i][2 + j] = __builtin_amdgcn_mfma_f32_16x16x32_bf16(aF[i][kh], bF1[j][kh], acc[4 + i][2 + j], 0, 0, 0);
        __builtin_amdgcn_s_setprio(0);
    }

    float bsv[4];
#pragma unroll
    for (int j = 0; j < 4; ++j)
        bsv[j] = bias[bn * 256 + wc * 64 + j * 16 + cc];

#pragma unroll
    for (int i = 0; i < 8; ++i) {
#pragma unroll
        for (int j = 0; j < 4; ++j) {
            const int n = bn * 256 + wc * 64 + j * 16 + cc;
#pragma unroll
            for (int r = 0; r < 4; ++r) {
                const int row = bm * 256 + wr * 128 + i * 16 + quad * 4 + r;  // C/D: row=quad*4+reg, col=c
                const float val = acc[i][j][r] + bsv[j];
                size_t idx;
                if (trans) idx = ((size_t)(row >> 10) * HID + n) * SQ + (row & 1023);
                else       idx = (size_t)row * HID + n;
                if (outF32) ((float*)C)[cOff + idx] = val;
                else        ((unsigned short*)C)[cOff + idx] = f2bf(val);
            }
        }
    }
}

// Fused Q/K/V projection on the 256^2 core; blockIdx.z picks tensor.
__global__ __launch_bounds__(512) void gemm_qkv(
    const short* __restrict__ Aq, const short* __restrict__ Ak,
    const short* __restrict__ Av, const short* __restrict__ Wq_,
    const short* __restrict__ Wk_, const short* __restrict__ Wv_,
    const float* __restrict__ bq_, const float* __restrict__ bk_,
    const float* __restrict__ bv_, short* __restrict__ oq,
    short* __restrict__ ok, short* __restrict__ ov)
{
    __shared__ __align__(16) short As2[2][16384];   // 64 KB
    __shared__ __align__(16) short Bs2[2][16384];   // 64 KB

    const int z = blockIdx.z;
    const short* A    = z == 0 ? Aq  : (z == 1 ? Ak  : Av);
    const short* Bw   = z == 0 ? Wq_ : (z == 1 ? Wk_ : Wv_);
    const float* bias = z == 0 ? bq_ : (z == 1 ? bk_ : bv_);
    short* C          = z == 0 ? oq  : (z == 1 ? ok  : ov);

    // XCD swizzle: 16 consecutive nids (4 bm x all 4 bn) per XCD
    const int nwg = gridDim.x * gridDim.y;          // multiple of 8
    const int id  = blockIdx.y * gridDim.x + blockIdx.x;
    const int nid = (id & 7) * (nwg >> 3) + (id >> 3);
    const int bn = nid & 3, bm = nid >> 2;

    gemm256_core(A, Bw, bias, C, 0, bm, bn, z == 2, false, As2, Bs2);
}

// O-projection on the 256^2 core, fp32 out.
__global__ __launch_bounds__(512) void gemm_bt(
    const short* __restrict__ A, const short* __restrict__ Bw,
    const float* __restrict__ bias, float* __restrict__ C, size_t cOff)
{
    __shared__ __align__(16) short As2[2][16384];
    __shared__ __align__(16) short Bs2[2][16384];

    const int nwg = gridDim.x * gridDim.y;
    const int id  = blockIdx.y * gridDim.x + blockIdx.x;
    const int nid = (id & 7) * (nwg >> 3) + (id >> 3);
    const int bn = nid & 3, bm = nid >> 2;

    gemm256_core(A, Bw, bias, C, cOff, bm, bn, false, true, As2, Bs2);
}

// Fused attention, 64-key tiles (R12-proven). Block = 128 q-rows of (bl, h);
// wave = 32 q-rows. XCD swizzle keeps the 8 qb-blocks of one (h,bl) on one
// XCD (K/V L2-local). T5 setprio around MFMA clusters. Bias dwords for tile
// kt+1 prefetched into regs during PV. exp2 with prefolded log2e.
__global__ __launch_bounds__(256) void attn(
    const short* __restrict__ qh, const short* __restrict__ kh,
    const short* __restrict__ vht, const unsigned short* __restrict__ abc,
    const float* __restrict__ zbf, short* __restrict__ aout, int b0)
{
    __shared__ __align__(16) short Kf[4096];     // region sub*4+half*2+kb
    __shared__ __align__(16) short Vf[4096];     // region sub*4+dt
    __shared__ __align__(16) short Ps[4][2304];  // per-wave 32 x 72-stride
    __shared__ float Zs[1152];

    const int tid = threadIdx.x;
    const int w = tid >> 6, lane = tid & 63;
    const int quad = lane >> 4, c = lane & 15;

    int qb, h, bl;
    if (gridDim.z == 8) {
        const int B = blockIdx.x + (blockIdx.y << 3) + (blockIdx.z << 7);
        const int hb = (B >> 6) * 8 + (B & 7);
        qb = (B >> 3) & 7; h = hb & 15; bl = hb >> 4;
    } else {
        qb = blockIdx.x; h = blockIdx.y; bl = blockIdx.z;
    }
    const int b = b0 + bl;

    for (int j = tid; j < 1151; j += 256)
        Zs[j] = zbf[qb * 128 + j] * LOG2E;

    const size_t blS = (size_t)bl * SQ;

    bf16x8 qa[2][2];     // A-frag: A[m=lane&15][k=quad*8+j]
#pragma unroll
    for (int m = 0; m < 2; ++m)
#pragma unroll
        for (int half = 0; half < 2; ++half)
            qa[m][half] = *(const bf16x8*)(qh + (blS + qb * 128 + w * 32 + m * 16 + c) * HID
                                               + h * 64 + half * 32 + quad * 8);

    const short* kg = kh  + (blS + 2 * c + (w & 1)) * HID + h * 64 + (w >> 1) * 32 + quad * 8;
    const short* vg = vht + ((size_t)bl * HID + h * 64 + w * 16 + c) * SQ + quad * 8;
    const size_t bge = ((size_t)b * SQ + qb * 128 + w * 32 + quad * 4) * SQ;

    bf16x8 kv0 = *(const bf16x8*)kg, kv1 = *(const bf16x8*)(kg + 32 * HID);
    bf16x8 vv0 = *(const bf16x8*)vg, vv1 = *(const bf16x8*)(vg + 32);

    uint32_t bp[2][4][2];
    auto loadB = [&](int K0) {
#pragma unroll
        for (int m = 0; m < 2; ++m)
#pragma unroll
            for (int r = 0; r < 4; ++r)
#pragma unroll
                for (int sub = 0; sub < 2; ++sub)
                    bp[m][r][sub] = *(const uint32_t*)(abc + bge + (size_t)(m * 16 + r) * SQ
                                                        + K0 + sub * 32 + 2 * c);
    };
    loadB(0);

    floatx4 o[2][4] = {};
    float sume[2][4] = {};

    for (int kt = 0; kt < 16; ++kt) {
        __syncthreads();
        *(bf16x8*)(Kf + w * 512 + lane * 8)       = kv0;
        *(bf16x8*)(Kf + (w + 4) * 512 + lane * 8) = kv1;
        *(bf16x8*)(Vf + w * 512 + lane * 8)       = vv0;
        *(bf16x8*)(Vf + (w + 4) * 512 + lane * 8) = vv1;
        __syncthreads();

        if (kt < 15) {                            // prefetch next 64-key tile
            kg += 64 * HID; vg += 64;
            kv0 = *(const bf16x8*)kg; kv1 = *(const bf16x8*)(kg + 32 * HID);
            vv0 = *(const bf16x8*)vg; vv1 = *(const bf16x8*)(vg + 32);
        }

        floatx4 sc[2][2][2] = {};                 // [m][sub][kb]
        __builtin_amdgcn_s_setprio(1);
#pragma unroll
        for (int sub = 0; sub < 2; ++sub) {
            bf16x8 kf[2][2];
#pragma unroll
            for (int half = 0; half < 2; ++half)
#pragma unroll
                for (int kb = 0; kb < 2; ++kb)
                    kf[half][kb] = *(const bf16x8*)(Kf + (sub * 4 + half * 2 + kb) * 512 + lane * 8);
#pragma unroll
            for (int m = 0; m < 2; ++m)
#pragma unroll
                for (int kb = 0; kb < 2; ++kb) {
                    sc[m][sub][kb] = __builtin_amdgcn_mfma_f32_16x16x32_bf16(qa[m][0], kf[0][kb], sc[m][sub][kb], 0, 0, 0);
                    sc[m][sub][kb] = __builtin_amdgcn_mfma_f32_16x16x32_bf16(qa[m][1], kf[1][kb], sc[m][sub][kb], 0, 0, 0);
                }
        }
        __builtin_amdgcn_s_setprio(0);

        const int k0 = kt * 64;
#pragma unroll
        for (int m = 0; m < 2; ++m) {
#pragma unroll
            for (int r = 0; r < 4; ++r) {
                const int lrq = w * 32 + m * 16 + quad * 4 + r;
                const int tb = lrq + 1023 - k0;                   // Zs idx = tb - local key
#pragma unroll
                for (int sub = 0; sub < 2; ++sub) {
                    const int kl = sub * 32 + 2 * c;
                    const uint32_t bv_ = bp[m][r][sub];
                    const float z0 = Zs[tb - kl], z1 = Zs[tb - kl - 1];
                    const float s0 = sc[m][sub][0][r] * CEXP + z0 + b2f((unsigned short)(bv_ & 0xffffu));
                    const float s1 = sc[m][sub][1][r] * CEXP + z1
                                   + __builtin_bit_cast(float, bv_ & 0xffff0000u);
                    const float e0 = __builtin_amdgcn_exp2f(s0);
                    const float e1 = __builtin_amdgcn_exp2f(s1);
                    sume[m][r] += e0 + e1;
                    const uint32_t pp = (uint32_t)f2bf(e0) | ((uint32_t)f2bf(e1) << 16);
                    *(uint32_t*)(&Ps[w][0] + (m * 16 + quad * 4 + r) * 72 + kl) = pp;
                }
            }
        }

        if (kt < 15) loadB(k0 + 64);              // hide bias latency under PV

        __builtin_amdgcn_s_setprio(1);
#pragma unroll
        for (int sub = 0; sub < 2; ++sub) {
            bf16x8 ap[2];
#pragma unroll
            for (int m = 0; m < 2; ++m)
                ap[m] = *(const bf16x8*)(&Ps[w][0] + (m * 16 + c) * 72 + sub * 32 + quad * 8);
#pragma unroll
            for (int dt = 0; dt < 4; ++dt) {
                const bf16x8 vf = *(const bf16x8*)(Vf + (sub * 4 + dt) * 512 + lane * 8);
#pragma unroll
                for (int m = 0; m < 2; ++m)
                    o[m][dt] = __builtin_amdgcn_mfma_f32_16x16x32_bf16(ap[m], vf, o[m][dt], 0, 0, 0);
            }
        }
        __builtin_amdgcn_s_setprio(0);
    }

#pragma unroll
    for (int m = 0; m < 2; ++m)
#pragma unroll
        for (int r = 0; r < 4; ++r) {
            float s = sume[m][r];
            s += __shfl_xor(s, 1);
            s += __shfl_xor(s, 2);
            s += __shfl_xor(s, 4);
            s += __shfl_xor(s, 8);
            sume[m][r] = 1.0f / s;
        }

#pragma unroll
    for (int m = 0; m < 2; ++m)
#pragma unroll
        for (int dt = 0; dt < 4; ++dt)
#pragma unroll
            for (int r = 0; r < 4; ++r) {
                const size_t row = blS + qb * 128 + w * 32 + m * 16 + quad * 4 + r;
                ((unsigned short*)aout)[row * HID + h * 64 + dt * 16 + c] =
                    f2bf(o[m][dt][r] * sume[m][r]);
            }
}

extern "C" void kernel_launch(void* const* d_in, const int* in_sizes, int n_in,
                              void* d_out, int out_size, void* d_ws, size_t ws_size,
                              hipStream_t stream) {
    const float* q  = (const float*)d_in[0];
    const float* k  = (const float*)d_in[1];
    const float* v  = (const float*)d_in[2];
    const float* ab = (const float*)d_in[3];
    const float* Wq = (const float*)d_in[4];  const float* bq = (const float*)d_in[5];
    const float* Wk = (const float*)d_in[6];  const float* bk = (const float*)d_in[7];
    const float* Wv = (const float*)d_in[8];  const float* bv = (const float*)d_in[9];
    const float* Wo = (const float*)d_in[10]; const float* bo = (const float*)d_in[11];
    const float* zb = (const float*)d_in[12];

    const size_t perB = (size_t)SQ * HID;            // 1M elems per batch
    const size_t WN   = (size_t)HID * HID;           // 1M elems per weight

    // ws: 4 bf16 weights (8MB) + bf16 attn_bias (16MB) + 6 x G x 2MB
    // (cbq,cbk,cbv, qh,khp,vht; ao aliases cbq).
    int G = 8;
    while (G > 1 && 24ull * 1024 * 1024 + 12ull * G * perB > ws_size) G >>= 1;

    unsigned short* Wqc = (unsigned short*)d_ws;
    unsigned short* Wkc = Wqc + WN;
    unsigned short* Wvc = Wkc + WN;
    unsigned short* Woc = Wvc + WN;
    unsigned short* abc = Woc + WN;                  // 8M elems (all batches)
    short* cbq = (short*)(abc + 8 * perB);           // bf16 A staging (q,k,v)
    short* cbk = cbq + (size_t)G * perB;
    short* cbv = cbk + (size_t)G * perB;
    short* qh  = cbv + (size_t)G * perB;
    short* khp = qh  + (size_t)G * perB;
    short* vht = khp + (size_t)G * perB;
    short* ao  = cbq;                                // alias: cb* dead after QKV

    const int ngroups = 8 / G;
    const int cn4 = (int)(G * perB / 4);
    const int cgrid = (cn4 + 255) / 256;
    const int mb = G * 4;                            // 256-row M-blocks (G*1024/256)

    cvt4<<<dim3((WN / 4 + 255) / 256, 4), 256, 0, stream>>>(
        Wq, Wk, Wv, Wo, Wqc, Wkc, Wvc, Woc, (int)(WN / 4));
    cvt<<<(8 * perB / 4 + 255) / 256, 256, 0, stream>>>(ab, abc, 8 * perB / 4, LOG2E);

    for (int g = 0; g < ngroups; ++g) {
        const size_t off = (size_t)g * G * perB;
        cvt3<<<dim3(cgrid, 3), 256, 0, stream>>>(
            q + off, k + off, v + off,
            (unsigned short*)cbq, (unsigned short*)cbk, (unsigned short*)cbv, cn4);
        gemm_qkv<<<dim3(4, mb, 3), dim3(512), 0, stream>>>(
            cbq, cbk, cbv, (short*)Wqc, (short*)Wkc, (short*)Wvc,
            bq, bk, bv, qh, khp, vht);
        attn<<<dim3(8, 16, G), dim3(256), 0, stream>>>(qh, khp, vht, abc, zb, ao, g * G);
        gemm_bt<<<dim3(4, mb), dim3(512), 0, stream>>>(ao, (short*)Woc, bo, (float*)d_out, off);
    }
}